// Round 21
// baseline (149.157 us; speedup 1.0000x reference)
//
#include <hip/hip_runtime.h>

typedef unsigned short u16;
typedef __attribute__((ext_vector_type(8))) short bf16x8;
typedef __attribute__((ext_vector_type(4))) float f32x4;

#define GLOAD_LDS16(gsrc, ldst)                                               \
  __builtin_amdgcn_global_load_lds(                                           \
      (const __attribute__((address_space(1))) void*)(gsrc),                  \
      (__attribute__((address_space(3))) void*)(ldst), 16, 0, 0)

#define LDSOFF(p) \
  ((unsigned)(uintptr_t)(__attribute__((address_space(3))) const void*)(p))

#define SB0 __builtin_amdgcn_sched_barrier(0)

__device__ __forceinline__ u16 f2bf(float x) {
  unsigned u = __float_as_uint(x);
  u = (u + 0x7FFFu + ((u >> 16) & 1u)) >> 16;
  return (u16)u;
}
__device__ __forceinline__ float bf2f(u16 v) {
  return __uint_as_float((unsigned)v << 16);
}

// ---------- prep: l1/l2/l3 -> bf16 [512][288], append 1 at col 256, zero-pad ----------
__global__ void prep_l_kernel(const float* __restrict__ l1,
                              const float* __restrict__ l2,
                              const float* __restrict__ l3,
                              u16* __restrict__ o1, u16* __restrict__ o2,
                              u16* __restrict__ o3) {
  int idx = blockIdx.x * 256 + threadIdx.x;
  const int NR = 512 * 288;
  if (idx >= 3 * NR) return;
  int which = idx / NR, rem = idx - which * NR;
  int r = rem / 288, p = rem - r * 288;
  const float* s = which == 0 ? l1 : which == 1 ? l2 : l3;
  u16* d = which == 0 ? o1 : which == 1 ? o2 : o3;
  float v = (p < 256) ? s[r * 256 + p] : (p == 256 ? 1.0f : 0.0f);
  d[rem] = f2bf(v);
}

// ---------- prep: W[a][b][c] fp32 -> W2[c][264 b][288 a] bf16, zero-padded ----------
// grid (5,5,264); every consumed byte rewritten each call (W2 lives in d_out).
__global__ __launch_bounds__(256, 4) void prep_w_kernel(
    const float* __restrict__ W, u16* __restrict__ W2) {
  __shared__ float tf[64][65];
  const int a0 = blockIdx.x * 64, c0 = blockIdx.y * 64, b = blockIdx.z;  // b<264
  const int t = threadIdx.x;
  const bool bok = (b < 257);

  float v[16];
#pragma unroll
  for (int i = 0; i < 16; ++i) {
    int idx = t + i * 256;
    int ar = idx >> 6, cc = idx & 63;
    int a = a0 + ar, c = c0 + cc;
    v[i] = (bok && a < 257 && c < 257) ? W[((long)a * 257 + b) * 257 + c] : 0.0f;
  }
#pragma unroll
  for (int i = 0; i < 16; ++i) {
    int idx = t + i * 256;
    int ar = idx >> 6, cc = idx & 63;
    tf[cc][ar] = v[i];
  }
  __syncthreads();

#pragma unroll
  for (int p = 0; p < 2; ++p) {
    int q = t + p * 256;
    int cr = q >> 3, ach = q & 7;
    int c = c0 + cr;
    int abase = a0 + ach * 8;
    if (c < 288 && abase < 288) {
      u16 pk[8];
#pragma unroll
      for (int j = 0; j < 8; ++j) pk[j] = f2bf(tf[cr][ach * 8 + j]);
      *(uint4*)(&W2[((long)c * 264 + b) * 288 + abase]) = *(uint4*)pk;
    }
  }
}

// ---------- stage-1 NT GEMM: 128x128 tile, 4 waves, 3 blocks/CU, dbuf ----------
// C[512][n=(c*264+b)] = l1b[512][288a] @ W2[n][288a]^T; 568 n-tiles, ldc 72704.
__global__ __launch_bounds__(256, 3) void gemm_nt(
    const u16* __restrict__ A, const u16* __restrict__ B, u16* __restrict__ C,
    int K, int lda, int ldb, int ldc) {
  __shared__ u16 As[2][4096];
  __shared__ u16 Bs[2][4096];
  const int t = threadIdx.x;
  const int bid = blockIdx.x;
  const int xcd = bid & 7, s = bid >> 3;
  const int nt = xcd * 71 + (s >> 2);
  const int mt = s & 3;
  const int m0 = mt * 128, n0 = nt * 128;
  const int lane = t & 63;
  const int w = t >> 6;
  const int wr = (w >> 1) * 64, wc = (w & 1) * 64;
  const int r16 = lane & 15;
  const int cgrp = lane >> 4;
  const int rr = cgrp * 4;
  const unsigned ABase = LDSOFF(&As[0][0]);
  const unsigned BBase = LDSOFF(&Bs[0][0]);
  (void)K;

  const u16* PA = A + (long)m0 * lda;
  const u16* PB = B + (long)n0 * ldb;

#define STG(buf, k0)                                                          \
  {                                                                           \
    _Pragma("unroll") for (int _p = 0; _p < 2; ++_p) {                        \
      int _q = t + _p * 256;                                                  \
      int _r = _q >> 2, _g = (_q & 3) ^ ((_r >> 1) & 3);                      \
      GLOAD_LDS16(PA + (long)_r * lda + (k0) + _g * 8, &As[buf][_q * 8]);     \
      GLOAD_LDS16(PB + (long)_r * ldb + (k0) + _g * 8, &Bs[buf][_q * 8]);     \
    }                                                                         \
  }

  f32x4 acc[4][4];
  const f32x4 zero = {0.f, 0.f, 0.f, 0.f};
#pragma unroll
  for (int i = 0; i < 4; ++i)
#pragma unroll
    for (int j = 0; j < 4; ++j) acc[i][j] = zero;

  STG(0, 0);

#define GCOL(NI)                                                              \
  __builtin_amdgcn_s_setprio(1);                                              \
  _Pragma("unroll") for (int _mi = 0; _mi < 4; ++_mi)                         \
    acc[_mi][NI] = __builtin_amdgcn_mfma_f32_16x16x32_bf16(                   \
        af[_mi], bf[NI], acc[_mi][NI], 0, 0, 0);                              \
  __builtin_amdgcn_s_setprio(0);                                              \
  SB0;

#define GSTEP(KS)                                                             \
  {                                                                           \
    asm volatile("s_waitcnt vmcnt(0)" ::: "memory");                          \
    SB0;                                                                      \
    __builtin_amdgcn_s_barrier();                                             \
    SB0;                                                                      \
    bf16x8 af[4], bf[4];                                                      \
    _Pragma("unroll") for (int mi = 0; mi < 4; ++mi) {                        \
      int R = wr + mi * 16 + r16;                                             \
      unsigned ao = ABase + (unsigned)(((((KS) & 1) * 4096) + R * 32 +        \
                                       ((cgrp ^ ((R >> 1) & 3)) * 8)) * 2);   \
      asm volatile("ds_read_b128 %0, %1" : "=v"(af[mi]) : "v"(ao));           \
    }                                                                         \
    _Pragma("unroll") for (int ni = 0; ni < 4; ++ni) {                        \
      int R = wc + ni * 16 + r16;                                             \
      unsigned ao = BBase + (unsigned)(((((KS) & 1) * 4096) + R * 32 +        \
                                       ((cgrp ^ ((R >> 1) & 3)) * 8)) * 2);   \
      asm volatile("ds_read_b128 %0, %1" : "=v"(bf[ni]) : "v"(ao));           \
    }                                                                         \
    SB0;                                                                      \
    if ((KS) < 8) STG(((KS) + 1) & 1, ((KS) + 1) * 32);                       \
    SB0;                                                                      \
    asm volatile("s_waitcnt lgkmcnt(3)" ::: "memory"); SB0;                   \
    GCOL(0)                                                                   \
    asm volatile("s_waitcnt lgkmcnt(2)" ::: "memory"); SB0;                   \
    GCOL(1)                                                                   \
    asm volatile("s_waitcnt lgkmcnt(1)" ::: "memory"); SB0;                   \
    GCOL(2)                                                                   \
    asm volatile("s_waitcnt lgkmcnt(0)" ::: "memory"); SB0;                   \
    GCOL(3)                                                                   \
  }

  GSTEP(0) GSTEP(1) GSTEP(2) GSTEP(3) GSTEP(4)
  GSTEP(5) GSTEP(6) GSTEP(7) GSTEP(8)
#undef GSTEP
#undef GCOL
#undef STG

#pragma unroll
  for (int mi = 0; mi < 4; ++mi) {
    int gm = m0 + wr + mi * 16 + rr;
#pragma unroll
    for (int ni = 0; ni < 4; ++ni) {
      int gc = n0 + wc + ni * 16 + r16;
#pragma unroll
      for (int r = 0; r < 4; ++r)
        C[(long)(gm + r) * ldc + gc] = f2bf(acc[mi][ni][r]);
    }
  }
}

// ---------- fused stage 2+3 (v7: v6 + ones-column hoisted to acc-init) ----------
// Phase A: S[64j][c<272] = T1[c][256] + l2b[j][b<256].T1[c][b<256]   (8 steps)
//   acc INITIALIZED to ov = T1[c][256] (l2b[:,256]==1); ov loaded in prologue
//   overlapping slab DMAs -- no epilogue serialization (R20 lesson).
// Phase B: out[j][k] = sum_{c<256} S[j][c].l3b[k][c] + S[j][256]     (8 steps)
__global__ __launch_bounds__(512, 4) void fused23(
    const u16* __restrict__ l2b, const u16* __restrict__ l3b,
    const u16* __restrict__ T1, float* __restrict__ out) {
  __shared__ u16 S[64 * 280];     // 35,840 B
  __shared__ u16 Bst[2][8704];    // 2 x 17,408 B -> total 70,656 B (2 blk/CU)
  const int t = threadIdx.x;
  const int lane = t & 63;
  const int w = t >> 6;  // 0..7

  const int bid = blockIdx.x;        // 0..2047
  const int xcd = bid & 7;
  const int seq = bid >> 3;          // 0..255
  const int ni = xcd * 64 + (seq >> 2);
  const int q = seq & 3;             // j-quarter (64 rows)
  const int n = ni >> 8;

  const int r16 = lane & 15;
  const int cgrp = lane >> 4;  // 0..3
  const int kb = cgrp * 8;
  const int rr = cgrp * 4;

  const u16* A2 = l2b + (long)n * 73728 + (long)(q * 64) * 288;  // [64][288]
  const u16* BT = T1 + (long)ni * 72704;                         // [c][264 b]
  const u16* B3 = l3b + (long)n * 73728;                         // [256][288]
  const unsigned BOF = LDSOFF(&Bst[0][0]);
  const unsigned SOF = LDSOFF(&S[0]);

  // A slab [272 c-rows][32 b]: 1088 chunks; wave owns 136 (2 full + lane<8).
#define ISSUE_A(buf, kk)                                                      \
  {                                                                           \
    int _q1 = w * 136 + lane;                                                 \
    int _r1 = _q1 >> 2, _g1 = (_q1 & 3) ^ ((_r1 >> 1) & 3);                   \
    GLOAD_LDS16(BT + (long)_r1 * 264 + (kk) * 32 + _g1 * 8,                   \
                &Bst[(buf)][_q1 * 8]);                                        \
    int _q2 = _q1 + 64;                                                       \
    int _r2 = _q2 >> 2, _g2 = (_q2 & 3) ^ ((_r2 >> 1) & 3);                   \
    GLOAD_LDS16(BT + (long)_r2 * 264 + (kk) * 32 + _g2 * 8,                   \
                &Bst[(buf)][_q2 * 8]);                                        \
    if (lane < 8) {                                                           \
      int _q3 = w * 136 + 128 + lane;                                         \
      int _r3 = _q3 >> 2, _g3 = (_q3 & 3) ^ ((_r3 >> 1) & 3);                 \
      GLOAD_LDS16(BT + (long)_r3 * 264 + (kk) * 32 + _g3 * 8,                 \
                  &Bst[(buf)][_q3 * 8]);                                      \
    }                                                                         \
  }
  // B slab [256 k-rows][32 c]: 1024 chunks; wave owns 128 (2 full).
#define ISSUE_B(buf, kk)                                                      \
  {                                                                           \
    _Pragma("unroll") for (int _p = 0; _p < 2; ++_p) {                        \
      int _q = w * 128 + lane + _p * 64;                                      \
      int _r = _q >> 2, _g = (_q & 3) ^ ((_r >> 1) & 3);                      \
      GLOAD_LDS16(B3 + (long)_r * 288 + (kk) * 32 + _g * 8,                   \
                  &Bst[(buf)][_q * 8]);                                       \
    }                                                                         \
  }

  // ================= phase A (K = 256 over b, 8 steps; acc init = ones-col) ===
  {
    const int wj = w & 3, wc2 = w >> 2;   // 16 j-rows; c-group {144,128}
    const int NT = 9 - wc2;               // 9 or 8 c-tiles

    ISSUE_A(0, 0) SB0;

    // ones-column loads overlap the slab DMAs (and all 8 steps below)
    f32x4 acc[9];
#pragma unroll
    for (int nj = 0; nj < 9; ++nj) if (nj < NT) {
      const int R = wc2 * 144 + nj * 16 + r16;
      float ov = bf2f(BT[(long)R * 264 + 256]);
      acc[nj][0] = ov; acc[nj][1] = ov; acc[nj][2] = ov; acc[nj][3] = ov;
    }
    SB0;
    ISSUE_A(1, 1) SB0;

    const u16* Ap = A2 + (long)(wj * 16 + r16) * 288 + kb;
    bf16x8 afc = *(const bf16x8*)(Ap);
    bf16x8 afn;
    SB0;

#define FA_STEP(K)                                                            \
  {                                                                           \
    asm volatile("s_waitcnt vmcnt(0)" ::: "memory");                          \
    SB0;                                                                      \
    __builtin_amdgcn_s_barrier();                                             \
    SB0;                                                                      \
    bf16x8 bf[9];                                                             \
    _Pragma("unroll") for (int nj = 0; nj < 9; ++nj) if (nj < NT) {           \
      const int R = wc2 * 144 + nj * 16 + r16;                                \
      unsigned ao = BOF + (unsigned)((((K) & 1) * 8704 + R * 32 +             \
                                      ((cgrp ^ ((R >> 1) & 3)) * 8)) * 2);    \
      asm volatile("ds_read_b128 %0, %1" : "=v"(bf[nj]) : "v"(ao));           \
    }                                                                         \
    SB0;                                                                      \
    if ((K) < 7) {                                                            \
      ISSUE_A(((K) + 1) & 1, (K) + 1);                                        \
      afn = *(const bf16x8*)(Ap + ((K) + 1) * 32);                            \
    }                                                                         \
    SB0;                                                                      \
    asm volatile("s_waitcnt lgkmcnt(0)" ::: "memory");                        \
    SB0;                                                                      \
    __builtin_amdgcn_s_setprio(1);                                            \
    _Pragma("unroll") for (int nj = 0; nj < 9; ++nj) if (nj < NT)             \
      acc[nj] = __builtin_amdgcn_mfma_f32_16x16x32_bf16(                      \
          afc, bf[nj], acc[nj], 0, 0, 0);                                     \
    __builtin_amdgcn_s_setprio(0);                                            \
    SB0;                                                                      \
    afc = afn;                                                                \
  }
    FA_STEP(0) FA_STEP(1) FA_STEP(2) FA_STEP(3)
    FA_STEP(4) FA_STEP(5) FA_STEP(6) FA_STEP(7)
#undef FA_STEP

    __syncthreads();  // all slab reads done; Bst reusable
    ISSUE_B(0, 0);
#pragma unroll
    for (int nj = 0; nj < 9; ++nj) if (nj < NT)
#pragma unroll
      for (int qq = 0; qq < 4; ++qq)
        S[(wj * 16 + rr + qq) * 280 + wc2 * 144 + nj * 16 + r16] =
            f2bf(acc[nj][qq]);
  }
  __syncthreads();  // S visible; ISSUE_B(0) drained at first FB wait

  // ================= phase B =================
  {
    const int wjb = w & 1, wk = w >> 1;  // 32 j-rows x 64 k-cols
    f32x4 acc[2][4];
    const f32x4 zero = {0.f, 0.f, 0.f, 0.f};
#pragma unroll
    for (int i = 0; i < 2; ++i)
#pragma unroll
      for (int j = 0; j < 4; ++j) acc[i][j] = zero;

#define FB_MM(NI)                                                             \
  __builtin_amdgcn_s_setprio(1);                                              \
  acc[0][NI] = __builtin_amdgcn_mfma_f32_16x16x32_bf16(af[0], bf[NI], acc[0][NI], 0, 0, 0); \
  acc[1][NI] = __builtin_amdgcn_mfma_f32_16x16x32_bf16(af[1], bf[NI], acc[1][NI], 0, 0, 0); \
  __builtin_amdgcn_s_setprio(0);                                              \
  SB0;

#define FB_STEP(K)                                                            \
  {                                                                           \
    asm volatile("s_waitcnt vmcnt(0)" ::: "memory");                          \
    SB0;                                                                      \
    __builtin_amdgcn_s_barrier();                                             \
    SB0;                                                                      \
    bf16x8 af[2], bf[4];                                                      \
    _Pragma("unroll") for (int mi = 0; mi < 2; ++mi) {                        \
      unsigned ao = SOF + (unsigned)(((wjb * 32 + mi * 16 + r16) * 280 +      \
                                      (K) * 32 + kb) * 2);                    \
      asm volatile("ds_read_b128 %0, %1" : "=v"(af[mi]) : "v"(ao));           \
    }                                                                         \
    _Pragma("unroll") for (int nj = 0; nj < 4; ++nj) {                        \
      const int R = wk * 64 + nj * 16 + r16;                                  \
      unsigned ao = BOF + (unsigned)((((K) & 1) * 8704 + R * 32 +             \
                                      ((cgrp ^ ((R >> 1) & 3)) * 8)) * 2);    \
      asm volatile("ds_read_b128 %0, %1" : "=v"(bf[nj]) : "v"(ao));           \
    }                                                                         \
    SB0;                                                                      \
    if ((K) < 7) ISSUE_B(((K) + 1) & 1, (K) + 1);                             \
    SB0;                                                                      \
    asm volatile("s_waitcnt lgkmcnt(3)" ::: "memory"); SB0;                   \
    FB_MM(0)                                                                  \
    asm volatile("s_waitcnt lgkmcnt(2)" ::: "memory"); SB0;                   \
    FB_MM(1)                                                                  \
    asm volatile("s_waitcnt lgkmcnt(1)" ::: "memory"); SB0;                   \
    FB_MM(2)                                                                  \
    asm volatile("s_waitcnt lgkmcnt(0)" ::: "memory"); SB0;                   \
    FB_MM(3)                                                                  \
  }
    FB_STEP(0) FB_STEP(1) FB_STEP(2) FB_STEP(3)
    FB_STEP(4) FB_STEP(5) FB_STEP(6) FB_STEP(7)
#undef FB_STEP
#undef FB_MM

    // ones-column: out[j][k] += S[j][256] (l3 col 256 == 1, cols 257.. == 0)
    float s256[2][4];
#pragma unroll
    for (int mi = 0; mi < 2; ++mi)
#pragma unroll
      for (int qq = 0; qq < 4; ++qq)
        s256[mi][qq] = __uint_as_float(
            (unsigned)S[(wjb * 32 + mi * 16 + rr + qq) * 280 + 256] << 16);

    float* O = out + (long)ni * 65536 + (long)(q * 64 + wjb * 32) * 256 + wk * 64;
#pragma unroll
    for (int mi = 0; mi < 2; ++mi)
#pragma unroll
      for (int nj = 0; nj < 4; ++nj)
#pragma unroll
        for (int qq = 0; qq < 4; ++qq)
          O[(long)(mi * 16 + rr + qq) * 256 + nj * 16 + r16] =
              acc[mi][nj][qq] + s256[mi][qq];
  }
#undef ISSUE_A
#undef ISSUE_B
}

extern "C" void kernel_launch(void* const* d_in, const int* in_sizes, int n_in,
                              void* d_out, int out_size, void* d_ws, size_t ws_size,
                              hipStream_t stream) {
  const float* l1 = (const float*)d_in[0];
  const float* l2 = (const float*)d_in[1];
  const float* l3 = (const float*)d_in[2];
  const float* W = (const float*)d_in[3];
  float* out = (float*)d_out;
  char* ws = (char*)d_ws;

  const long LB = 512L * 288 * 2;
  u16* l1b = (u16*)ws;
  u16* l2b = (u16*)(ws + LB);
  u16* l3b = (u16*)(ws + 2 * LB);
  u16* T1 = (u16*)(ws + 3 * LB);  // [512][72704] bf16 = 74.4 MB ((c,b) b-compact 264)
  u16* W2 = (u16*)d_out;          // [288c][264b][288a] bf16; rewritten every call

  prep_l_kernel<<<1728, 256, 0, stream>>>(l1, l2, l3, l1b, l2b, l3b);

  dim3 gw(5, 5, 264);
  prep_w_kernel<<<gw, 256, 0, stream>>>(W, W2);

  // stage 1: T1[512][(c*264+b)] = l1b @ W2^T (568 n-tiles, ldc 72704)
  gemm_nt<<<2272, 256, 0, stream>>>(l1b, W2, T1, 288, 288, 288, 72704);

  // fused stage 2+3: 4 quarter-blocks per ni, XCD-grouped, 8 waves, 2 blk/CU
  fused23<<<2048, 512, 0, stream>>>(l2b, l3b, T1, out);
}

// Round 22
// 145.284 us; speedup vs baseline: 1.0267x; 1.0267x over previous
//
#include <hip/hip_runtime.h>

typedef unsigned short u16;
typedef __attribute__((ext_vector_type(8))) short bf16x8;
typedef __attribute__((ext_vector_type(4))) float f32x4;

#define GLOAD_LDS16(gsrc, ldst)                                               \
  __builtin_amdgcn_global_load_lds(                                           \
      (const __attribute__((address_space(1))) void*)(gsrc),                  \
      (__attribute__((address_space(3))) void*)(ldst), 16, 0, 0)

#define LDSOFF(p) \
  ((unsigned)(uintptr_t)(__attribute__((address_space(3))) const void*)(p))

#define SB0 __builtin_amdgcn_sched_barrier(0)

__device__ __forceinline__ u16 f2bf(float x) {
  unsigned u = __float_as_uint(x);
  u = (u + 0x7FFFu + ((u >> 16) & 1u)) >> 16;
  return (u16)u;
}

// ---------- prep: l1/l2/l3 -> bf16 [512][288], append 1 at col 256, zero-pad ----------
__global__ void prep_l_kernel(const float* __restrict__ l1,
                              const float* __restrict__ l2,
                              const float* __restrict__ l3,
                              u16* __restrict__ o1, u16* __restrict__ o2,
                              u16* __restrict__ o3) {
  int idx = blockIdx.x * 256 + threadIdx.x;
  const int NR = 512 * 288;
  if (idx >= 3 * NR) return;
  int which = idx / NR, rem = idx - which * NR;
  int r = rem / 288, p = rem - r * 288;
  const float* s = which == 0 ? l1 : which == 1 ? l2 : l3;
  u16* d = which == 0 ? o1 : which == 1 ? o2 : o3;
  float v = (p < 256) ? s[r * 256 + p] : (p == 256 ? 1.0f : 0.0f);
  d[rem] = f2bf(v);
}

// ---------- prep: W[a][b][c] fp32 -> W2[c][b][a] bf16, FULL 288^3 zero-padded ----------
__global__ __launch_bounds__(256, 4) void prep_w_kernel(
    const float* __restrict__ W, u16* __restrict__ W2) {
  __shared__ float tf[64][65];
  const int a0 = blockIdx.x * 64, c0 = blockIdx.y * 64, b = blockIdx.z;  // b<288
  const int t = threadIdx.x;
  const bool bok = (b < 257);

  float v[16];
#pragma unroll
  for (int i = 0; i < 16; ++i) {
    int idx = t + i * 256;
    int ar = idx >> 6, cc = idx & 63;
    int a = a0 + ar, c = c0 + cc;
    v[i] = (bok && a < 257 && c < 257) ? W[((long)a * 257 + b) * 257 + c] : 0.0f;
  }
#pragma unroll
  for (int i = 0; i < 16; ++i) {
    int idx = t + i * 256;
    int ar = idx >> 6, cc = idx & 63;
    tf[cc][ar] = v[i];
  }
  __syncthreads();

#pragma unroll
  for (int p = 0; p < 2; ++p) {
    int q = t + p * 256;
    int cr = q >> 3, ach = q & 7;
    int c = c0 + cr;
    int abase = a0 + ach * 8;
    if (c < 288 && abase < 288) {
      u16 pk[8];
#pragma unroll
      for (int j = 0; j < 8; ++j) pk[j] = f2bf(tf[cr][ach * 8 + j]);
      *(uint4*)(&W2[((long)c * 288 + b) * 288 + abase]) = *(uint4*)pk;
    }
  }
}

// ---------- stage-1 NT GEMM: 128x128 tile, 4 waves, 3 blocks/CU, dbuf ----------
// N trimmed to 616 tiles (T1 c-rows < 274; fused23 reads rows < 272 only).
__global__ __launch_bounds__(256, 3) void gemm_nt(
    const u16* __restrict__ A, const u16* __restrict__ B, u16* __restrict__ C,
    int K, int lda, int ldb, int ldc) {
  __shared__ u16 As[2][4096];
  __shared__ u16 Bs[2][4096];
  const int t = threadIdx.x;
  const int bid = blockIdx.x;
  const int xcd = bid & 7, s = bid >> 3;
  const int nt = xcd * 77 + (s >> 2);
  const int mt = s & 3;
  const int m0 = mt * 128, n0 = nt * 128;
  const int lane = t & 63;
  const int w = t >> 6;
  const int wr = (w >> 1) * 64, wc = (w & 1) * 64;
  const int r16 = lane & 15;
  const int cgrp = lane >> 4;
  const int rr = cgrp * 4;
  const unsigned ABase = LDSOFF(&As[0][0]);
  const unsigned BBase = LDSOFF(&Bs[0][0]);
  (void)K;

  const u16* PA = A + (long)m0 * lda;
  const u16* PB = B + (long)n0 * ldb;

#define STG(buf, k0)                                                          \
  {                                                                           \
    _Pragma("unroll") for (int _p = 0; _p < 2; ++_p) {                        \
      int _q = t + _p * 256;                                                  \
      int _r = _q >> 2, _g = (_q & 3) ^ ((_r >> 1) & 3);                      \
      GLOAD_LDS16(PA + (long)_r * lda + (k0) + _g * 8, &As[buf][_q * 8]);     \
      GLOAD_LDS16(PB + (long)_r * ldb + (k0) + _g * 8, &Bs[buf][_q * 8]);     \
    }                                                                         \
  }

  f32x4 acc[4][4];
  const f32x4 zero = {0.f, 0.f, 0.f, 0.f};
#pragma unroll
  for (int i = 0; i < 4; ++i)
#pragma unroll
    for (int j = 0; j < 4; ++j) acc[i][j] = zero;

  STG(0, 0);

#define GCOL(NI)                                                              \
  __builtin_amdgcn_s_setprio(1);                                              \
  _Pragma("unroll") for (int _mi = 0; _mi < 4; ++_mi)                         \
    acc[_mi][NI] = __builtin_amdgcn_mfma_f32_16x16x32_bf16(                   \
        af[_mi], bf[NI], acc[_mi][NI], 0, 0, 0);                              \
  __builtin_amdgcn_s_setprio(0);                                              \
  SB0;

#define GSTEP(KS)                                                             \
  {                                                                           \
    asm volatile("s_waitcnt vmcnt(0)" ::: "memory");                          \
    SB0;                                                                      \
    __builtin_amdgcn_s_barrier();                                             \
    SB0;                                                                      \
    bf16x8 af[4], bf[4];                                                      \
    _Pragma("unroll") for (int mi = 0; mi < 4; ++mi) {                        \
      int R = wr + mi * 16 + r16;                                             \
      unsigned ao = ABase + (unsigned)(((((KS) & 1) * 4096) + R * 32 +        \
                                       ((cgrp ^ ((R >> 1) & 3)) * 8)) * 2);   \
      asm volatile("ds_read_b128 %0, %1" : "=v"(af[mi]) : "v"(ao));           \
    }                                                                         \
    _Pragma("unroll") for (int ni = 0; ni < 4; ++ni) {                        \
      int R = wc + ni * 16 + r16;                                             \
      unsigned ao = BBase + (unsigned)(((((KS) & 1) * 4096) + R * 32 +        \
                                       ((cgrp ^ ((R >> 1) & 3)) * 8)) * 2);   \
      asm volatile("ds_read_b128 %0, %1" : "=v"(bf[ni]) : "v"(ao));           \
    }                                                                         \
    SB0;                                                                      \
    if ((KS) < 8) STG(((KS) + 1) & 1, ((KS) + 1) * 32);                       \
    SB0;                                                                      \
    asm volatile("s_waitcnt lgkmcnt(3)" ::: "memory"); SB0;                   \
    GCOL(0)                                                                   \
    asm volatile("s_waitcnt lgkmcnt(2)" ::: "memory"); SB0;                   \
    GCOL(1)                                                                   \
    asm volatile("s_waitcnt lgkmcnt(1)" ::: "memory"); SB0;                   \
    GCOL(2)                                                                   \
    asm volatile("s_waitcnt lgkmcnt(0)" ::: "memory"); SB0;                   \
    GCOL(3)                                                                   \
  }

  GSTEP(0) GSTEP(1) GSTEP(2) GSTEP(3) GSTEP(4)
  GSTEP(5) GSTEP(6) GSTEP(7) GSTEP(8)
#undef GSTEP
#undef GCOL
#undef STG

#pragma unroll
  for (int mi = 0; mi < 4; ++mi) {
    int gm = m0 + wr + mi * 16 + rr;
#pragma unroll
    for (int ni = 0; ni < 4; ++ni) {
      int gc = n0 + wc + ni * 16 + r16;
#pragma unroll
      for (int r = 0; r < 4; ++r)
        C[(long)(gm + r) * ldc + gc] = f2bf(acc[mi][ni][r]);
    }
  }
}

// ---------- fused stage 2+3 (R18 champion: R13 wave shape + c272 trim + ones) ----------
// Phase A: S[64j][c<272] = l2[n][j0+j][b] . T1[ni][c][b]   (K=b=288, 9 steps)
//   8 waves = 4 j-groups(16) x 2 c-groups {144,128}; NT = 9-wc2 tiles/wave;
//   acc[9]; A-frag reg-dbuf; slab [272r][32k] x2, drain vmcnt(0)/step.
// Phase B: out[ni][j][k] = sum_{c<256} S[j][c].l3[n][k][c] + S[j][256]
//   8 waves = 2 j-groups(32) x 4 k-groups(64); acc[2][4]; K=256, 8 steps.
__global__ __launch_bounds__(512, 4) void fused23(
    const u16* __restrict__ l2b, const u16* __restrict__ l3b,
    const u16* __restrict__ T1, float* __restrict__ out) {
  __shared__ u16 S[64 * 280];     // 35,840 B (stride 280: 2-way banks, free)
  __shared__ u16 Bst[2][8704];    // 2 x 17,408 B -> total 70,656 B (2 blk/CU)
  const int t = threadIdx.x;
  const int lane = t & 63;
  const int w = t >> 6;  // 0..7

  const int bid = blockIdx.x;        // 0..2047
  const int xcd = bid & 7;
  const int seq = bid >> 3;          // 0..255
  const int ni = xcd * 64 + (seq >> 2);
  const int q = seq & 3;             // j-quarter (64 rows)
  const int n = ni >> 8;

  const int r16 = lane & 15;
  const int cgrp = lane >> 4;  // 0..3
  const int kb = cgrp * 8;
  const int rr = cgrp * 4;
  const f32x4 zero = {0.f, 0.f, 0.f, 0.f};

  const u16* A2 = l2b + (long)n * 73728 + (long)(q * 64) * 288;  // [64][288]
  const u16* BT = T1 + (long)ni * 82944;                         // rows=(c,b)
  const u16* B3 = l3b + (long)n * 73728;                         // [256][288]
  const unsigned BOF = LDSOFF(&Bst[0][0]);
  const unsigned SOF = LDSOFF(&S[0]);

  // A slab [272r][32k]: 1088 chunks; wave owns 136 (2 full + lane<8).
#define ISSUE_A(buf, kk)                                                      \
  {                                                                           \
    int _q1 = w * 136 + lane;                                                 \
    int _r1 = _q1 >> 2, _g1 = (_q1 & 3) ^ ((_r1 >> 1) & 3);                   \
    GLOAD_LDS16(BT + (long)_r1 * 288 + (kk) * 32 + _g1 * 8,                   \
                &Bst[(buf)][_q1 * 8]);                                        \
    int _q2 = _q1 + 64;                                                       \
    int _r2 = _q2 >> 2, _g2 = (_q2 & 3) ^ ((_r2 >> 1) & 3);                   \
    GLOAD_LDS16(BT + (long)_r2 * 288 + (kk) * 32 + _g2 * 8,                   \
                &Bst[(buf)][_q2 * 8]);                                        \
    if (lane < 8) {                                                           \
      int _q3 = w * 136 + 128 + lane;                                         \
      int _r3 = _q3 >> 2, _g3 = (_q3 & 3) ^ ((_r3 >> 1) & 3);                 \
      GLOAD_LDS16(BT + (long)_r3 * 288 + (kk) * 32 + _g3 * 8,                 \
                  &Bst[(buf)][_q3 * 8]);                                      \
    }                                                                         \
  }
  // B slab [256r][32c]: 1024 chunks; wave owns 128 (2 full).
#define ISSUE_B(buf, kk)                                                      \
  {                                                                           \
    _Pragma("unroll") for (int _p = 0; _p < 2; ++_p) {                        \
      int _q = w * 128 + lane + _p * 64;                                      \
      int _r = _q >> 2, _g = (_q & 3) ^ ((_r >> 1) & 3);                      \
      GLOAD_LDS16(B3 + (long)_r * 288 + (kk) * 32 + _g * 8,                   \
                  &Bst[(buf)][_q * 8]);                                       \
    }                                                                         \
  }

  // ================= phase A =================
  {
    const int wj = w & 3, wc2 = w >> 2;   // 16 j-rows; c-group {144,128}
    const int NT = 9 - wc2;               // 9 or 8 c-tiles
    f32x4 acc[9];
#pragma unroll
    for (int j = 0; j < 9; ++j) acc[j] = zero;

    const u16* Ap = A2 + (long)(wj * 16 + r16) * 288 + kb;
    bf16x8 afc = *(const bf16x8*)(Ap);
    bf16x8 afn;
    SB0;
    ISSUE_A(0, 0) SB0;
    ISSUE_A(1, 1) SB0;

#define FA_STEP(K)                                                            \
  {                                                                           \
    asm volatile("s_waitcnt vmcnt(0)" ::: "memory");                          \
    SB0;                                                                      \
    __builtin_amdgcn_s_barrier();                                             \
    SB0;                                                                      \
    bf16x8 bf[9];                                                             \
    _Pragma("unroll") for (int nj = 0; nj < 9; ++nj) if (nj < NT) {           \
      const int R = wc2 * 144 + nj * 16 + r16;                                \
      unsigned ao = BOF + (unsigned)((((K) & 1) * 8704 + R * 32 +             \
                                      ((cgrp ^ ((R >> 1) & 3)) * 8)) * 2);    \
      asm volatile("ds_read_b128 %0, %1" : "=v"(bf[nj]) : "v"(ao));           \
    }                                                                         \
    SB0;                                                                      \
    if ((K) < 8) {                                                            \
      ISSUE_A(((K) + 1) & 1, (K) + 1);                                        \
      afn = *(const bf16x8*)(Ap + ((K) + 1) * 32);                            \
    }                                                                         \
    SB0;                                                                      \
    asm volatile("s_waitcnt lgkmcnt(0)" ::: "memory");                        \
    SB0;                                                                      \
    __builtin_amdgcn_s_setprio(1);                                            \
    _Pragma("unroll") for (int nj = 0; nj < 9; ++nj) if (nj < NT)             \
      acc[nj] = __builtin_amdgcn_mfma_f32_16x16x32_bf16(                      \
          afc, bf[nj], acc[nj], 0, 0, 0);                                     \
    __builtin_amdgcn_s_setprio(0);                                            \
    SB0;                                                                      \
    afc = afn;                                                                \
  }
    FA_STEP(0) FA_STEP(1) FA_STEP(2) FA_STEP(3) FA_STEP(4)
    FA_STEP(5) FA_STEP(6) FA_STEP(7) FA_STEP(8)
#undef FA_STEP

    __syncthreads();  // all slab reads done; Bst reusable
    ISSUE_B(0, 0);
#pragma unroll
    for (int nj = 0; nj < 9; ++nj) if (nj < NT)
#pragma unroll
      for (int qq = 0; qq < 4; ++qq)
        S[(wj * 16 + rr + qq) * 280 + wc2 * 144 + nj * 16 + r16] =
            f2bf(acc[nj][qq]);
  }
  __syncthreads();  // S visible; ISSUE_B(0) drained at first FB wait

  // ================= phase B =================
  {
    const int wjb = w & 1, wk = w >> 1;  // 32 j-rows x 64 k-cols
    f32x4 acc[2][4];
#pragma unroll
    for (int i = 0; i < 2; ++i)
#pragma unroll
      for (int j = 0; j < 4; ++j) acc[i][j] = zero;

#define FB_MM(NI)                                                             \
  __builtin_amdgcn_s_setprio(1);                                              \
  acc[0][NI] = __builtin_amdgcn_mfma_f32_16x16x32_bf16(af[0], bf[NI], acc[0][NI], 0, 0, 0); \
  acc[1][NI] = __builtin_amdgcn_mfma_f32_16x16x32_bf16(af[1], bf[NI], acc[1][NI], 0, 0, 0); \
  __builtin_amdgcn_s_setprio(0);                                              \
  SB0;

#define FB_STEP(K)                                                            \
  {                                                                           \
    asm volatile("s_waitcnt vmcnt(0)" ::: "memory");                          \
    SB0;                                                                      \
    __builtin_amdgcn_s_barrier();                                             \
    SB0;                                                                      \
    bf16x8 af[2], bf[4];                                                      \
    _Pragma("unroll") for (int mi = 0; mi < 2; ++mi) {                        \
      unsigned ao = SOF + (unsigned)(((wjb * 32 + mi * 16 + r16) * 280 +      \
                                      (K) * 32 + kb) * 2);                    \
      asm volatile("ds_read_b128 %0, %1" : "=v"(af[mi]) : "v"(ao));           \
    }                                                                         \
    _Pragma("unroll") for (int nj = 0; nj < 4; ++nj) {                        \
      const int R = wk * 64 + nj * 16 + r16;                                  \
      unsigned ao = BOF + (unsigned)((((K) & 1) * 8704 + R * 32 +             \
                                      ((cgrp ^ ((R >> 1) & 3)) * 8)) * 2);    \
      asm volatile("ds_read_b128 %0, %1" : "=v"(bf[nj]) : "v"(ao));           \
    }                                                                         \
    SB0;                                                                      \
    if ((K) < 7) ISSUE_B(((K) + 1) & 1, (K) + 1);                             \
    SB0;                                                                      \
    asm volatile("s_waitcnt lgkmcnt(3)" ::: "memory"); SB0;                   \
    FB_MM(0)                                                                  \
    asm volatile("s_waitcnt lgkmcnt(2)" ::: "memory"); SB0;                   \
    FB_MM(1)                                                                  \
    asm volatile("s_waitcnt lgkmcnt(1)" ::: "memory"); SB0;                   \
    FB_MM(2)                                                                  \
    asm volatile("s_waitcnt lgkmcnt(0)" ::: "memory"); SB0;                   \
    FB_MM(3)                                                                  \
  }
    FB_STEP(0) FB_STEP(1) FB_STEP(2) FB_STEP(3)
    FB_STEP(4) FB_STEP(5) FB_STEP(6) FB_STEP(7)
#undef FB_STEP
#undef FB_MM

    // ones-column: out[j][k] += S[j][256] (l3 col 256 == 1, cols 257.. == 0)
    float s256[2][4];
#pragma unroll
    for (int mi = 0; mi < 2; ++mi)
#pragma unroll
      for (int qq = 0; qq < 4; ++qq)
        s256[mi][qq] = __uint_as_float(
            (unsigned)S[(wjb * 32 + mi * 16 + rr + qq) * 280 + 256] << 16);

    float* O = out + (long)ni * 65536 + (long)(q * 64 + wjb * 32) * 256 + wk * 64;
#pragma unroll
    for (int mi = 0; mi < 2; ++mi)
#pragma unroll
      for (int nj = 0; nj < 4; ++nj)
#pragma unroll
        for (int qq = 0; qq < 4; ++qq)
          O[(long)(mi * 16 + rr + qq) * 256 + nj * 16 + r16] =
              acc[mi][nj][qq] + s256[mi][qq];
  }
#undef ISSUE_A
#undef ISSUE_B
}

extern "C" void kernel_launch(void* const* d_in, const int* in_sizes, int n_in,
                              void* d_out, int out_size, void* d_ws, size_t ws_size,
                              hipStream_t stream) {
  const float* l1 = (const float*)d_in[0];
  const float* l2 = (const float*)d_in[1];
  const float* l3 = (const float*)d_in[2];
  const float* W = (const float*)d_in[3];
  float* out = (float*)d_out;
  char* ws = (char*)d_ws;

  const long LB = 512L * 288 * 2;
  u16* l1b = (u16*)ws;
  u16* l2b = (u16*)(ws + LB);
  u16* l3b = (u16*)(ws + 2 * LB);
  u16* T1 = (u16*)(ws + 3 * LB);  // [512][(c,b) 82944] bf16 = 84.9 MB alloc
  u16* W2 = (u16*)d_out;          // staged in d_out; fully rewritten every call

  prep_l_kernel<<<1728, 256, 0, stream>>>(l1, l2, l3, l1b, l2b, l3b);

  dim3 gw(5, 5, 288);
  prep_w_kernel<<<gw, 256, 0, stream>>>(W, W2);

  // stage 1: T1[512][(c,b)] for c<274 (616 n-tiles; fused23 needs c<272)
  gemm_nt<<<2464, 256, 0, stream>>>(l1b, W2, T1, 288, 288, 288, 82944);

  // fused stage 2+3: 4 quarter-blocks per ni, XCD-grouped, 8 waves, 2 blk/CU
  fused23<<<2048, 512, 0, stream>>>(l2b, l3b, T1, out);
}